// Round 3
// baseline (209.977 us; speedup 1.0000x reference)
//
#include <hip/hip_runtime.h>
#include <math.h>

// Focal-weighted BCE-with-logits, mean-reduced. Single fused kernel:
// grid-stride partial sums + last-block-done final reduction (deterministic:
// last block reads partials in fixed index order).
//
// col = targ==1 ? 0 : targ==3 ? 1 : 2 ; t = onehot(col)
// w   = t ? (1-x)^2 : x^2
// bce = max(x,0) - x*t + log1p(exp(-|x|))
// out = mean(w * bce)

#define GRID  2048
#define BLOCK 256

// clang-native vectors: __builtin_nontemporal_load needs these (HIP float4 is a class)
typedef float f32x4 __attribute__((ext_vector_type(4)));
typedef int   i32x4 __attribute__((ext_vector_type(4)));

__device__ __forceinline__ float elem_loss(float x, bool is_t) {
    float l   = __logf(1.0f + __expf(-fabsf(x)));        // log1p(exp(-|x|))
    float bce = fmaxf(x, 0.0f) + l - (is_t ? x : 0.0f);
    float m   = is_t ? (1.0f - x) : x;                   // 1 - pt
    return m * m * bce;
}

__device__ __forceinline__ float group_loss(f32x4 f0, f32x4 f1, f32x4 f2, i32x4 tg) {
    float f[12] = {f0.x, f0.y, f0.z, f0.w,
                   f1.x, f1.y, f1.z, f1.w,
                   f2.x, f2.y, f2.z, f2.w};
    int   tt[4] = {tg.x, tg.y, tg.z, tg.w};
    float acc = 0.0f;
    #pragma unroll
    for (int a = 0; a < 4; ++a) {
        int col = (tt[a] == 1) ? 0 : ((tt[a] == 3) ? 1 : 2);
        #pragma unroll
        for (int j = 0; j < 3; ++j)
            acc += elem_loss(f[a * 3 + j], j == col);
    }
    return acc;
}

__global__ __launch_bounds__(BLOCK, 2) void focal_fused(
        const float* __restrict__ pred,
        const int*   __restrict__ targ,
        float*       __restrict__ partial,
        unsigned*    __restrict__ counter,
        float*       __restrict__ out,
        int n_anchors, float inv_total) {
    const int tid      = blockIdx.x * BLOCK + threadIdx.x;
    const int nthreads = GRID * BLOCK;
    const int groups   = n_anchors >> 2;                 // 4 anchors / group

    const f32x4* __restrict__ p4 = (const f32x4*)pred;
    const i32x4* __restrict__ t4 = (const i32x4*)targ;

    float acc = 0.0f;
    int g = tid;

    // Unroll-by-4: 12 f32x4 + 4 i32x4 independent nontemporal loads in flight
    // before any compute (256 B/thread).
    for (; g + 3 * nthreads < groups; g += 4 * nthreads) {
        const int g0 = g, g1 = g + nthreads, g2 = g + 2 * nthreads, g3 = g + 3 * nthreads;
        f32x4 a0 = __builtin_nontemporal_load(p4 + 3 * g0 + 0);
        f32x4 a1 = __builtin_nontemporal_load(p4 + 3 * g0 + 1);
        f32x4 a2 = __builtin_nontemporal_load(p4 + 3 * g0 + 2);
        f32x4 b0 = __builtin_nontemporal_load(p4 + 3 * g1 + 0);
        f32x4 b1 = __builtin_nontemporal_load(p4 + 3 * g1 + 1);
        f32x4 b2 = __builtin_nontemporal_load(p4 + 3 * g1 + 2);
        f32x4 c0 = __builtin_nontemporal_load(p4 + 3 * g2 + 0);
        f32x4 c1 = __builtin_nontemporal_load(p4 + 3 * g2 + 1);
        f32x4 c2 = __builtin_nontemporal_load(p4 + 3 * g2 + 2);
        f32x4 d0 = __builtin_nontemporal_load(p4 + 3 * g3 + 0);
        f32x4 d1 = __builtin_nontemporal_load(p4 + 3 * g3 + 1);
        f32x4 d2 = __builtin_nontemporal_load(p4 + 3 * g3 + 2);
        i32x4 ta = __builtin_nontemporal_load(t4 + g0);
        i32x4 tb = __builtin_nontemporal_load(t4 + g1);
        i32x4 tc = __builtin_nontemporal_load(t4 + g2);
        i32x4 td = __builtin_nontemporal_load(t4 + g3);

        acc += group_loss(a0, a1, a2, ta);
        acc += group_loss(b0, b1, b2, tb);
        acc += group_loss(c0, c1, c2, tc);
        acc += group_loss(d0, d1, d2, td);
    }
    for (; g < groups; g += nthreads) {
        f32x4 a0 = __builtin_nontemporal_load(p4 + 3 * g + 0);
        f32x4 a1 = __builtin_nontemporal_load(p4 + 3 * g + 1);
        f32x4 a2 = __builtin_nontemporal_load(p4 + 3 * g + 2);
        i32x4 ta = __builtin_nontemporal_load(t4 + g);
        acc += group_loss(a0, a1, a2, ta);
    }
    // scalar tail (none for A = 8388608; defensive)
    for (int i = (groups << 2) + tid; i < n_anchors; i += nthreads) {
        int tv  = targ[i];
        int col = (tv == 1) ? 0 : ((tv == 3) ? 1 : 2);
        #pragma unroll
        for (int j = 0; j < 3; ++j)
            acc += elem_loss(pred[i * 3 + j], j == col);
    }

    // block reduction: wave-64 shuffle, then LDS across 4 waves
    #pragma unroll
    for (int off = 32; off; off >>= 1)
        acc += __shfl_down(acc, off, 64);

    __shared__ float sm[4];
    __shared__ bool  sm_last;
    const int lane = threadIdx.x & 63;
    const int wave = threadIdx.x >> 6;
    if (lane == 0) sm[wave] = acc;
    __syncthreads();

    if (threadIdx.x == 0) {
        float s = sm[0] + sm[1] + sm[2] + sm[3];
        __hip_atomic_store(&partial[blockIdx.x], s, __ATOMIC_RELEASE,
                           __HIP_MEMORY_SCOPE_AGENT);
        unsigned prev = __hip_atomic_fetch_add(counter, 1u, __ATOMIC_ACQ_REL,
                                               __HIP_MEMORY_SCOPE_AGENT);
        sm_last = (prev == GRID - 1);
    }
    __syncthreads();

    if (sm_last) {                                       // exactly one block runs this
        float facc = 0.0f;
        for (int i = threadIdx.x; i < GRID; i += BLOCK)  // fixed order → deterministic
            facc += __hip_atomic_load(&partial[i], __ATOMIC_RELAXED,
                                      __HIP_MEMORY_SCOPE_AGENT);
        #pragma unroll
        for (int off = 32; off; off >>= 1)
            facc += __shfl_down(facc, off, 64);
        __syncthreads();                                 // sm[] reuse
        if (lane == 0) sm[wave] = facc;
        __syncthreads();
        if (threadIdx.x == 0)
            out[0] = (sm[0] + sm[1] + sm[2] + sm[3]) * inv_total;
    }
}

extern "C" void kernel_launch(void* const* d_in, const int* in_sizes, int n_in,
                              void* d_out, int out_size, void* d_ws, size_t ws_size,
                              hipStream_t stream) {
    const float* pred = (const float*)d_in[0];
    const int*   targ = (const int*)d_in[1];
    float*       out  = (float*)d_out;

    unsigned* counter = (unsigned*)d_ws;                       // 4 B
    float*    partial = (float*)((char*)d_ws + 256);           // GRID floats

    const int n_anchors = in_sizes[1];
    const float inv_total = 1.0f / (3.0f * (float)n_anchors);

    hipMemsetAsync(counter, 0, sizeof(unsigned), stream);      // ticket reset, every call
    focal_fused<<<GRID, BLOCK, 0, stream>>>(pred, targ, partial, counter, out,
                                            n_anchors, inv_total);
}

// Round 4
// 140.427 us; speedup vs baseline: 1.4953x; 1.4953x over previous
//
#include <hip/hip_runtime.h>
#include <math.h>

// Focal-weighted BCE-with-logits, mean-reduced. Single fused kernel:
// grid-stride partial sums + last-block-done final reduction (deterministic:
// last block reads partials in fixed index order).
//
// Round-3 lesson: NO nontemporal hints — inputs (128 MB) are L3-resident
// across graph replays, and nt defeats both L1 line-reuse (48B-stride
// pattern) and L3 retention. Plain cached loads.
//
// col = targ==1 ? 0 : targ==3 ? 1 : 2 ; t = onehot(col)
// w   = t ? (1-x)^2 : x^2
// bce = max(x,0) - x*t + log1p(exp(-|x|))
// out = mean(w * bce)

#define GRID  2048
#define BLOCK 256

typedef float f32x4 __attribute__((ext_vector_type(4)));
typedef int   i32x4 __attribute__((ext_vector_type(4)));

__device__ __forceinline__ float elem_loss(float x, bool is_t) {
    float l   = __logf(1.0f + __expf(-fabsf(x)));        // log1p(exp(-|x|))
    float bce = fmaxf(x, 0.0f) + l - (is_t ? x : 0.0f);
    float m   = is_t ? (1.0f - x) : x;                   // 1 - pt
    return m * m * bce;
}

__device__ __forceinline__ float group_loss(f32x4 f0, f32x4 f1, f32x4 f2, i32x4 tg) {
    float f[12] = {f0.x, f0.y, f0.z, f0.w,
                   f1.x, f1.y, f1.z, f1.w,
                   f2.x, f2.y, f2.z, f2.w};
    int   tt[4] = {tg.x, tg.y, tg.z, tg.w};
    float acc = 0.0f;
    #pragma unroll
    for (int a = 0; a < 4; ++a) {
        int col = (tt[a] == 1) ? 0 : ((tt[a] == 3) ? 1 : 2);
        #pragma unroll
        for (int j = 0; j < 3; ++j)
            acc += elem_loss(f[a * 3 + j], j == col);
    }
    return acc;
}

__global__ __launch_bounds__(BLOCK) void focal_fused(
        const float* __restrict__ pred,
        const int*   __restrict__ targ,
        float*       __restrict__ partial,
        unsigned*    __restrict__ counter,
        float*       __restrict__ out,
        int n_anchors, float inv_total) {
    const int tid      = blockIdx.x * BLOCK + threadIdx.x;
    const int nthreads = GRID * BLOCK;
    const int groups   = n_anchors >> 2;                 // 4 anchors / group

    const f32x4* __restrict__ p4 = (const f32x4*)pred;
    const i32x4* __restrict__ t4 = (const i32x4*)targ;

    float acc = 0.0f;

    // 4 iterations at these sizes; 3x f32x4 + 1x i32x4 = 64 B/thread/iter,
    // wave-contiguous span (all bytes used) -> L1 merges the 48B-stride overlap.
    for (int g = tid; g < groups; g += nthreads) {
        f32x4 f0 = p4[3 * g + 0];
        f32x4 f1 = p4[3 * g + 1];
        f32x4 f2 = p4[3 * g + 2];
        i32x4 tg = t4[g];
        acc += group_loss(f0, f1, f2, tg);
    }
    // scalar tail (none for A = 8388608; defensive)
    for (int i = (groups << 2) + tid; i < n_anchors; i += nthreads) {
        int tv  = targ[i];
        int col = (tv == 1) ? 0 : ((tv == 3) ? 1 : 2);
        #pragma unroll
        for (int j = 0; j < 3; ++j)
            acc += elem_loss(pred[i * 3 + j], j == col);
    }

    // block reduction: wave-64 shuffle, then LDS across 4 waves
    #pragma unroll
    for (int off = 32; off; off >>= 1)
        acc += __shfl_down(acc, off, 64);

    __shared__ float sm[4];
    __shared__ bool  sm_last;
    const int lane = threadIdx.x & 63;
    const int wave = threadIdx.x >> 6;
    if (lane == 0) sm[wave] = acc;
    __syncthreads();

    if (threadIdx.x == 0) {
        float s = sm[0] + sm[1] + sm[2] + sm[3];
        __hip_atomic_store(&partial[blockIdx.x], s, __ATOMIC_RELEASE,
                           __HIP_MEMORY_SCOPE_AGENT);
        unsigned prev = __hip_atomic_fetch_add(counter, 1u, __ATOMIC_ACQ_REL,
                                               __HIP_MEMORY_SCOPE_AGENT);
        sm_last = (prev == GRID - 1);
    }
    __syncthreads();

    if (sm_last) {                                       // exactly one block runs this
        float facc = 0.0f;
        for (int i = threadIdx.x; i < GRID; i += BLOCK)  // fixed order -> deterministic
            facc += __hip_atomic_load(&partial[i], __ATOMIC_RELAXED,
                                      __HIP_MEMORY_SCOPE_AGENT);
        #pragma unroll
        for (int off = 32; off; off >>= 1)
            facc += __shfl_down(facc, off, 64);
        __syncthreads();                                 // sm[] reuse
        if (lane == 0) sm[wave] = facc;
        __syncthreads();
        if (threadIdx.x == 0)
            out[0] = (sm[0] + sm[1] + sm[2] + sm[3]) * inv_total;
    }
}

extern "C" void kernel_launch(void* const* d_in, const int* in_sizes, int n_in,
                              void* d_out, int out_size, void* d_ws, size_t ws_size,
                              hipStream_t stream) {
    const float* pred = (const float*)d_in[0];
    const int*   targ = (const int*)d_in[1];
    float*       out  = (float*)d_out;

    unsigned* counter = (unsigned*)d_ws;                       // 4 B
    float*    partial = (float*)((char*)d_ws + 256);           // GRID floats

    const int n_anchors = in_sizes[1];
    const float inv_total = 1.0f / (3.0f * (float)n_anchors);

    hipMemsetAsync(counter, 0, sizeof(unsigned), stream);      // ticket reset, every call
    focal_fused<<<GRID, BLOCK, 0, stream>>>(pred, targ, partial, counter, out,
                                            n_anchors, inv_total);
}

// Round 5
// 48.679 us; speedup vs baseline: 4.3135x; 2.8847x over previous
//
#include <hip/hip_runtime.h>
#include <math.h>

// Focal-weighted BCE-with-logits, mean-reduced. Single fused kernel:
// grid-stride partial sums + last-block-done final reduction (deterministic:
// last block reads partials in fixed index order).
//
// Round-4 lesson: agent-scope RELEASE/ACQUIRE atomics emit buffer_wbl2 /
// buffer_inv (full L2 writeback/invalidate) per block on gfx950 -> 2048
// cache nukes under the streaming loads = 4-6x slowdown. Use RELAXED
// cache-bypassing atomics only; order partial-store before ticket with an
// explicit s_waitcnt vmcnt(0). Relaxed agent-scope atomics are coherent at
// the coherence point (sc flags) without cache maintenance.
//
// col = targ==1 ? 0 : targ==3 ? 1 : 2 ; t = onehot(col)
// w   = t ? (1-x)^2 : x^2
// bce = max(x,0) - x*t + log1p(exp(-|x|))
// out = mean(w * bce)

#define GRID  2048
#define BLOCK 256

typedef float f32x4 __attribute__((ext_vector_type(4)));
typedef int   i32x4 __attribute__((ext_vector_type(4)));

__device__ __forceinline__ float elem_loss(float x, bool is_t) {
    float l   = __logf(1.0f + __expf(-fabsf(x)));        // log1p(exp(-|x|))
    float bce = fmaxf(x, 0.0f) + l - (is_t ? x : 0.0f);
    float m   = is_t ? (1.0f - x) : x;                   // 1 - pt
    return m * m * bce;
}

__device__ __forceinline__ float group_loss(f32x4 f0, f32x4 f1, f32x4 f2, i32x4 tg) {
    float f[12] = {f0.x, f0.y, f0.z, f0.w,
                   f1.x, f1.y, f1.z, f1.w,
                   f2.x, f2.y, f2.z, f2.w};
    int   tt[4] = {tg.x, tg.y, tg.z, tg.w};
    float acc = 0.0f;
    #pragma unroll
    for (int a = 0; a < 4; ++a) {
        int col = (tt[a] == 1) ? 0 : ((tt[a] == 3) ? 1 : 2);
        #pragma unroll
        for (int j = 0; j < 3; ++j)
            acc += elem_loss(f[a * 3 + j], j == col);
    }
    return acc;
}

__global__ __launch_bounds__(BLOCK) void focal_fused(
        const float* __restrict__ pred,
        const int*   __restrict__ targ,
        float*       __restrict__ partial,
        unsigned*    __restrict__ counter,
        float*       __restrict__ out,
        int n_anchors, float inv_total) {
    const int tid      = blockIdx.x * BLOCK + threadIdx.x;
    const int nthreads = GRID * BLOCK;
    const int groups   = n_anchors >> 2;                 // 4 anchors / group

    const f32x4* __restrict__ p4 = (const f32x4*)pred;
    const i32x4* __restrict__ t4 = (const i32x4*)targ;

    float acc = 0.0f;

    // 4 iterations at these sizes; 3x f32x4 + 1x i32x4 = 64 B/thread/iter,
    // wave-contiguous span (all bytes used) -> L1 merges the 48B-stride overlap.
    for (int g = tid; g < groups; g += nthreads) {
        f32x4 f0 = p4[3 * g + 0];
        f32x4 f1 = p4[3 * g + 1];
        f32x4 f2 = p4[3 * g + 2];
        i32x4 tg = t4[g];
        acc += group_loss(f0, f1, f2, tg);
    }
    // scalar tail (none for A = 8388608; defensive)
    for (int i = (groups << 2) + tid; i < n_anchors; i += nthreads) {
        int tv  = targ[i];
        int col = (tv == 1) ? 0 : ((tv == 3) ? 1 : 2);
        #pragma unroll
        for (int j = 0; j < 3; ++j)
            acc += elem_loss(pred[i * 3 + j], j == col);
    }

    // block reduction: wave-64 shuffle, then LDS across 4 waves
    #pragma unroll
    for (int off = 32; off; off >>= 1)
        acc += __shfl_down(acc, off, 64);

    __shared__ float sm[4];
    __shared__ bool  sm_last;
    const int lane = threadIdx.x & 63;
    const int wave = threadIdx.x >> 6;
    if (lane == 0) sm[wave] = acc;
    __syncthreads();

    if (threadIdx.x == 0) {
        float s = sm[0] + sm[1] + sm[2] + sm[3];
        // RELAXED atomic store: cache-bypassing (coherent at agent scope),
        // NO buffer_wbl2. Ordering vs the ticket via explicit vmcnt drain.
        __hip_atomic_store(&partial[blockIdx.x], s, __ATOMIC_RELAXED,
                           __HIP_MEMORY_SCOPE_AGENT);
        asm volatile("s_waitcnt vmcnt(0)" ::: "memory");
        unsigned prev = __hip_atomic_fetch_add(counter, 1u, __ATOMIC_RELAXED,
                                               __HIP_MEMORY_SCOPE_AGENT);
        sm_last = (prev == GRID - 1);
    }
    __syncthreads();

    if (sm_last) {                                       // exactly one block runs this
        float facc = 0.0f;
        for (int i = threadIdx.x; i < GRID; i += BLOCK)  // fixed order -> deterministic
            facc += __hip_atomic_load(&partial[i], __ATOMIC_RELAXED,
                                      __HIP_MEMORY_SCOPE_AGENT);
        #pragma unroll
        for (int off = 32; off; off >>= 1)
            facc += __shfl_down(facc, off, 64);
        __syncthreads();                                 // sm[] reuse
        if (lane == 0) sm[wave] = facc;
        __syncthreads();
        if (threadIdx.x == 0)
            out[0] = (sm[0] + sm[1] + sm[2] + sm[3]) * inv_total;
    }
}

extern "C" void kernel_launch(void* const* d_in, const int* in_sizes, int n_in,
                              void* d_out, int out_size, void* d_ws, size_t ws_size,
                              hipStream_t stream) {
    const float* pred = (const float*)d_in[0];
    const int*   targ = (const int*)d_in[1];
    float*       out  = (float*)d_out;

    unsigned* counter = (unsigned*)d_ws;                       // 4 B
    float*    partial = (float*)((char*)d_ws + 256);           // GRID floats

    const int n_anchors = in_sizes[1];
    const float inv_total = 1.0f / (3.0f * (float)n_anchors);

    hipMemsetAsync(counter, 0, sizeof(unsigned), stream);      // ticket reset, every call
    focal_fused<<<GRID, BLOCK, 0, stream>>>(pred, targ, partial, counter, out,
                                            n_anchors, inv_total);
}

// Round 6
// 29.141 us; speedup vs baseline: 7.2054x; 1.6704x over previous
//
#include <hip/hip_runtime.h>
#include <math.h>

// Focal-weighted BCE-with-logits, mean-reduced. TWO kernels (round-5 lesson:
// fused last-block ticket costs ~16us in same-address agent RMW serialization
// + cache-bypass stores; plain-memory two-kernel graph is faster).
//
// Main kernel: 1M threads, exactly 2 groups (8 anchors) per thread, all 8
// vector loads issued before compute (MLP), two independent accumulators.
//
// col = targ==1 ? 0 : targ==3 ? 1 : 2 ; t = onehot(col)
// w   = t ? (1-x)^2 : x^2
// bce = max(x,0) - x*t + log1p(exp(-|x|))
// out = mean(w * bce)

#define GRID   4096
#define BLOCK  256
#define FBLOCK 1024

typedef float f32x4 __attribute__((ext_vector_type(4)));
typedef int   i32x4 __attribute__((ext_vector_type(4)));

__device__ __forceinline__ float elem_loss(float x, bool is_t) {
    float l   = __logf(1.0f + __expf(-fabsf(x)));        // log1p(exp(-|x|))
    float bce = fmaxf(x, 0.0f) + l - (is_t ? x : 0.0f);
    float m   = is_t ? (1.0f - x) : x;                   // 1 - pt
    return m * m * bce;
}

__device__ __forceinline__ float group_loss(f32x4 f0, f32x4 f1, f32x4 f2, i32x4 tg) {
    float f[12] = {f0.x, f0.y, f0.z, f0.w,
                   f1.x, f1.y, f1.z, f1.w,
                   f2.x, f2.y, f2.z, f2.w};
    int   tt[4] = {tg.x, tg.y, tg.z, tg.w};
    float acc = 0.0f;
    #pragma unroll
    for (int a = 0; a < 4; ++a) {
        int col = (tt[a] == 1) ? 0 : ((tt[a] == 3) ? 1 : 2);
        #pragma unroll
        for (int j = 0; j < 3; ++j)
            acc += elem_loss(f[a * 3 + j], j == col);
    }
    return acc;
}

__global__ __launch_bounds__(BLOCK) void focal_partial(
        const float* __restrict__ pred,
        const int*   __restrict__ targ,
        float*       __restrict__ partial,
        int n_anchors) {
    const int tid      = blockIdx.x * BLOCK + threadIdx.x;
    const int nthreads = GRID * BLOCK;
    const int groups   = n_anchors >> 2;                 // 4 anchors / group

    const f32x4* __restrict__ p4 = (const f32x4*)pred;
    const i32x4* __restrict__ t4 = (const i32x4*)targ;

    float acc0 = 0.0f, acc1 = 0.0f;
    int g = tid;

    // Pairwise: 8 independent vector loads in flight before any compute.
    for (; g + nthreads < groups; g += 2 * nthreads) {
        const int g0 = g, g1 = g + nthreads;
        f32x4 a0 = p4[3 * g0 + 0];
        f32x4 a1 = p4[3 * g0 + 1];
        f32x4 a2 = p4[3 * g0 + 2];
        f32x4 b0 = p4[3 * g1 + 0];
        f32x4 b1 = p4[3 * g1 + 1];
        f32x4 b2 = p4[3 * g1 + 2];
        i32x4 ta = t4[g0];
        i32x4 tb = t4[g1];
        acc0 += group_loss(a0, a1, a2, ta);
        acc1 += group_loss(b0, b1, b2, tb);
    }
    for (; g < groups; g += nthreads) {                  // odd remainder
        f32x4 a0 = p4[3 * g + 0];
        f32x4 a1 = p4[3 * g + 1];
        f32x4 a2 = p4[3 * g + 2];
        i32x4 ta = t4[g];
        acc0 += group_loss(a0, a1, a2, ta);
    }
    // scalar tail (none for A = 8388608; defensive)
    for (int i = (groups << 2) + tid; i < n_anchors; i += nthreads) {
        int tv  = targ[i];
        int col = (tv == 1) ? 0 : ((tv == 3) ? 1 : 2);
        #pragma unroll
        for (int j = 0; j < 3; ++j)
            acc0 += elem_loss(pred[i * 3 + j], j == col);
    }

    float acc = acc0 + acc1;

    // wave-64 shuffle reduce, then LDS across 4 waves
    #pragma unroll
    for (int off = 32; off; off >>= 1)
        acc += __shfl_down(acc, off, 64);

    __shared__ float sm[4];
    const int lane = threadIdx.x & 63;
    const int wave = threadIdx.x >> 6;
    if (lane == 0) sm[wave] = acc;
    __syncthreads();

    if (threadIdx.x == 0)
        partial[blockIdx.x] = sm[0] + sm[1] + sm[2] + sm[3];
}

__global__ __launch_bounds__(FBLOCK) void final_reduce(
        const float* __restrict__ partial, int nparts,
        float* __restrict__ out, float inv_total) {
    const f32x4* __restrict__ p4 = (const f32x4*)partial;
    float acc = 0.0f;
    for (int i = threadIdx.x; 4 * i < nparts; i += FBLOCK) {
        f32x4 v = p4[i];                                 // 1 load/thread at 4096 parts
        acc += (v.x + v.y) + (v.z + v.w);
    }

    #pragma unroll
    for (int off = 32; off; off >>= 1)
        acc += __shfl_down(acc, off, 64);

    __shared__ float sm[FBLOCK / 64];
    const int lane = threadIdx.x & 63;
    const int wave = threadIdx.x >> 6;
    if (lane == 0) sm[wave] = acc;
    __syncthreads();

    if (threadIdx.x == 0) {
        float s = 0.0f;
        #pragma unroll
        for (int w = 0; w < FBLOCK / 64; ++w) s += sm[w];
        out[0] = s * inv_total;
    }
}

extern "C" void kernel_launch(void* const* d_in, const int* in_sizes, int n_in,
                              void* d_out, int out_size, void* d_ws, size_t ws_size,
                              hipStream_t stream) {
    const float* pred = (const float*)d_in[0];
    const int*   targ = (const int*)d_in[1];
    float*       out  = (float*)d_out;
    float*       partial = (float*)d_ws;                 // GRID floats, 16B-aligned

    const int n_anchors = in_sizes[1];
    const float inv_total = 1.0f / (3.0f * (float)n_anchors);

    focal_partial<<<GRID, BLOCK, 0, stream>>>(pred, targ, partial, n_anchors);
    final_reduce<<<1, FBLOCK, 0, stream>>>(partial, GRID, out, inv_total);
}

// Round 7
// 28.325 us; speedup vs baseline: 7.4132x; 1.0288x over previous
//
#include <hip/hip_runtime.h>
#include <math.h>

// Focal-weighted BCE-with-logits, mean-reduced. TWO kernels, plain memory
// (round-5 lesson: fused last-block ticket = agent-RMW serialization, slow).
//
// Round-7 structure: 2M threads, EXACTLY ONE 4-anchor group per thread
// (3x f32x4 + 1x i32x4 = 64 B), max thread-level parallelism for latency
// hiding; occupancy was the round-6 limiter (52%), not VGPRs or BW.
//
// col = targ==1 ? 0 : targ==3 ? 1 : 2 ; t = onehot(col)
// w   = t ? (1-x)^2 : x^2
// bce = max(x,0) - x*t + log1p(exp(-|x|))
// out = mean(w * bce)

#define GRID   8192
#define BLOCK  256
#define FBLOCK 1024

typedef float f32x4 __attribute__((ext_vector_type(4)));
typedef int   i32x4 __attribute__((ext_vector_type(4)));

__device__ __forceinline__ float elem_loss(float x, bool is_t) {
    float l   = __logf(1.0f + __expf(-fabsf(x)));        // log1p(exp(-|x|))
    float bce = fmaxf(x, 0.0f) + l - (is_t ? x : 0.0f);
    float m   = is_t ? (1.0f - x) : x;                   // 1 - pt
    return m * m * bce;
}

__device__ __forceinline__ float group_loss(f32x4 f0, f32x4 f1, f32x4 f2, i32x4 tg) {
    float f[12] = {f0.x, f0.y, f0.z, f0.w,
                   f1.x, f1.y, f1.z, f1.w,
                   f2.x, f2.y, f2.z, f2.w};
    int   tt[4] = {tg.x, tg.y, tg.z, tg.w};
    float acc = 0.0f;
    #pragma unroll
    for (int a = 0; a < 4; ++a) {
        int col = (tt[a] == 1) ? 0 : ((tt[a] == 3) ? 1 : 2);
        #pragma unroll
        for (int j = 0; j < 3; ++j)
            acc += elem_loss(f[a * 3 + j], j == col);
    }
    return acc;
}

__global__ __launch_bounds__(BLOCK) void focal_partial(
        const float* __restrict__ pred,
        const int*   __restrict__ targ,
        float*       __restrict__ partial,
        int n_anchors) {
    const int tid      = blockIdx.x * BLOCK + threadIdx.x;
    const int nthreads = GRID * BLOCK;
    const int groups   = n_anchors >> 2;                 // 4 anchors / group

    const f32x4* __restrict__ p4 = (const f32x4*)pred;
    const i32x4* __restrict__ t4 = (const i32x4*)targ;

    float acc = 0.0f;

    // Exactly 1 iteration at A=8388608 (2M groups / 2M threads); loop kept
    // for generality. 4 independent vector loads, then compute.
    for (int g = tid; g < groups; g += nthreads) {
        f32x4 f0 = p4[3 * g + 0];
        f32x4 f1 = p4[3 * g + 1];
        f32x4 f2 = p4[3 * g + 2];
        i32x4 tg = t4[g];
        acc += group_loss(f0, f1, f2, tg);
    }
    // scalar tail (none for A = 8388608; defensive)
    for (int i = (groups << 2) + tid; i < n_anchors; i += nthreads) {
        int tv  = targ[i];
        int col = (tv == 1) ? 0 : ((tv == 3) ? 1 : 2);
        #pragma unroll
        for (int j = 0; j < 3; ++j)
            acc += elem_loss(pred[i * 3 + j], j == col);
    }

    // wave-64 shuffle reduce, then LDS across 4 waves
    #pragma unroll
    for (int off = 32; off; off >>= 1)
        acc += __shfl_down(acc, off, 64);

    __shared__ float sm[4];
    const int lane = threadIdx.x & 63;
    const int wave = threadIdx.x >> 6;
    if (lane == 0) sm[wave] = acc;
    __syncthreads();

    if (threadIdx.x == 0)
        partial[blockIdx.x] = sm[0] + sm[1] + sm[2] + sm[3];
}

__global__ __launch_bounds__(FBLOCK) void final_reduce(
        const float* __restrict__ partial, int nparts,
        float* __restrict__ out, float inv_total) {
    const f32x4* __restrict__ p4 = (const f32x4*)partial;
    float acc = 0.0f;
    for (int i = threadIdx.x; 4 * i < nparts; i += FBLOCK) {
        f32x4 v = p4[i];                                 // 2 loads/thread at 8192 parts
        acc += (v.x + v.y) + (v.z + v.w);
    }

    #pragma unroll
    for (int off = 32; off; off >>= 1)
        acc += __shfl_down(acc, off, 64);

    __shared__ float sm[FBLOCK / 64];
    const int lane = threadIdx.x & 63;
    const int wave = threadIdx.x >> 6;
    if (lane == 0) sm[wave] = acc;
    __syncthreads();

    if (threadIdx.x == 0) {
        float s = 0.0f;
        #pragma unroll
        for (int w = 0; w < FBLOCK / 64; ++w) s += sm[w];
        out[0] = s * inv_total;
    }
}

extern "C" void kernel_launch(void* const* d_in, const int* in_sizes, int n_in,
                              void* d_out, int out_size, void* d_ws, size_t ws_size,
                              hipStream_t stream) {
    const float* pred = (const float*)d_in[0];
    const int*   targ = (const int*)d_in[1];
    float*       out  = (float*)d_out;
    float*       partial = (float*)d_ws;                 // GRID floats, 16B-aligned

    const int n_anchors = in_sizes[1];
    const float inv_total = 1.0f / (3.0f * (float)n_anchors);

    focal_partial<<<GRID, BLOCK, 0, stream>>>(pred, targ, partial, n_anchors);
    final_reduce<<<1, FBLOCK, 0, stream>>>(partial, GRID, out, inv_total);
}